// Round 19
// baseline (129.777 us; speedup 1.0000x reference)
//
#include <hip/hip_runtime.h>
#include <hip/hip_bf16.h>

typedef __attribute__((ext_vector_type(8))) _Float16 hfx8;
typedef __attribute__((ext_vector_type(16))) float fx16;
typedef __attribute__((ext_vector_type(2))) __fp16 fp16x2;
typedef __attribute__((ext_vector_type(4))) float fx4;
typedef __attribute__((ext_vector_type(4))) unsigned short usx4;
typedef __attribute__((ext_vector_type(8))) unsigned short usx8;
typedef __attribute__((ext_vector_type(2))) unsigned int ux2;

#define LOG2E 1.44269504f

__device__ __forceinline__ unsigned short f2h(float f) {
  union { _Float16 h; unsigned short u; } c;
  c.h = (_Float16)f;
  return c.u;
}

__device__ __forceinline__ void async16(const void* g, void* l) {
  __builtin_amdgcn_global_load_lds(
      (const __attribute__((address_space(1))) void*)g,
      (__attribute__((address_space(3))) void*)l, 16, 0, 0);
}

// f32 -> fp16, 1024 elements per block
__global__ __launch_bounds__(256)
void cvth(const float* __restrict__ s, unsigned short* __restrict__ d) {
  int i = (blockIdx.x * 256 + threadIdx.x) * 4;
  fx4 v = *(const fx4*)(s + i);
  usx4 o;
  o[0] = f2h(v[0]); o[1] = f2h(v[1]); o[2] = f2h(v[2]); o[3] = f2h(v[3]);
  *(usx4*)(d + i) = o;
}

// 4 weight matrices f32 -> fp16; grid.y selects
__global__ __launch_bounds__(256)
void cvtw(const float* __restrict__ s0, const float* __restrict__ s1,
          const float* __restrict__ s2, const float* __restrict__ s3,
          unsigned short* __restrict__ d0, unsigned short* __restrict__ d1,
          unsigned short* __restrict__ d2, unsigned short* __restrict__ d3) {
  const int y = blockIdx.y;
  const float* s = (y == 0) ? s0 : (y == 1) ? s1 : (y == 2) ? s2 : s3;
  unsigned short* d = (y == 0) ? d0 : (y == 1) ? d1 : (y == 2) ? d2 : d3;
  int i = (blockIdx.x * 256 + threadIdx.x) * 4;
  fx4 v = *(const fx4*)(s + i);
  usx4 o;
  o[0] = f2h(v[0]); o[1] = f2h(v[1]); o[2] = f2h(v[2]); o[3] = f2h(v[3]);
  *(usx4*)(d + i) = o;
}

// Per-batch mask scan: src[b*2048 + c] = source row s of compact index c;
// cnt[b] = number of unmasked keys. One block per batch, 256 thr x 8.
__global__ __launch_bounds__(256)
void maskscan(const int* __restrict__ mask, int* __restrict__ src, int* __restrict__ cnt) {
  const int b = blockIdx.x;
  const int tid = threadIdx.x;
  const int base = b * 2048 + tid * 8;
  int m[8];
  int s = 0;
#pragma unroll
  for (int e = 0; e < 8; ++e) { m[e] = mask[base + e] ? 1 : 0; s += m[e]; }
  const int lane = tid & 63, wv = tid >> 6;
  int inc = s;
#pragma unroll
  for (int off = 1; off < 64; off <<= 1) {
    int t = __shfl_up(inc, off);
    if (lane >= off) inc += t;
  }
  __shared__ int wsum[4];
  if (lane == 63) wsum[wv] = inc;
  __syncthreads();
  int wvoff = 0;
#pragma unroll
  for (int k = 0; k < 4; ++k)
    if (k < wv) wvoff += wsum[k];
  int run = wvoff + inc - s;  // exclusive prefix (in-batch)
#pragma unroll
  for (int e = 0; e < 8; ++e) {
    if (m[e]) { src[b * 2048 + run] = tid * 8 + e; ++run; }
  }
  if (tid == 255) cnt[b] = run;
}

// QKV projection fp16. Linear grid 768, XCD-chunk swizzled (768 = 8*96).
// m97-style SINGLE-buffered LDS (32 KB).
// sel=0: Q dense, mt 0..31, output *ATT_SCALE.
// sel=1/2: K/V over COMPACTED rows via src[] gather; early-exit past cnt.
__global__ __launch_bounds__(256, 4)
void gemm_qkv(const unsigned short* __restrict__ A,
              const unsigned short* __restrict__ Wq,
              const unsigned short* __restrict__ Wk,
              const unsigned short* __restrict__ Wv,
              const int* __restrict__ src, const int* __restrict__ cnt,
              unsigned short* __restrict__ Qf, unsigned short* __restrict__ Kf,
              unsigned short* __restrict__ Vt) {
  __shared__ unsigned short As[128 * 64];
  __shared__ unsigned short Bs[128 * 64];
  const int tid = threadIdx.x;
  const int w = tid >> 6, ln = tid & 63;
  const int bid = blockIdx.x;
  const int wg = (bid & 7) * 96 + (bid >> 3);  // XCD-chunk swizzle (bijective)
  const int mt = wg & 31;
  const int by = wg >> 5;
  const int sel = by >> 3;
  const int nt = by & 7;
  const unsigned short* W = (sel == 0) ? Wq : ((sel == 1) ? Wk : Wv);
  const int n0 = nt * 128;
  const int wr = w >> 1, wc = w & 1;

  const int lr = ln >> 3;
  const int scg = (ln & 7) ^ lr;

  // A-row source pointers (block-constant per lane)
  const int bI = mt >> 4;
  const int r0 = (mt & 15) * 128;
  int cnt_b = 0;
  const unsigned short* Arow[4];
  if (sel == 0) {
    const int m0 = mt * 128;
#pragma unroll
    for (int ii = 0; ii < 4; ++ii)
      Arow[ii] = A + (size_t)(m0 + w * 32 + ii * 8 + lr) * 1024 + scg * 8;
  } else {
    cnt_b = cnt[bI];
    if (r0 >= cnt_b) return;
#pragma unroll
    for (int ii = 0; ii < 4; ++ii) {
      int r = r0 + w * 32 + ii * 8 + lr;
      r = (r < cnt_b) ? r : (cnt_b - 1);
      Arow[ii] = A + (size_t)(bI * 2048 + src[bI * 2048 + r]) * 1024 + scg * 8;
    }
  }
  const unsigned short* Bsrc = W + (size_t)(n0 + w * 32 + lr) * 1024 + scg * 8;

  fx4 acc[4][4] = {};

  for (int kt = 0; kt < 16; ++kt) {
#pragma unroll
    for (int i = 0; i < 4; ++i) {
      async16(Arow[i] + kt * 64, &As[(w * 32 + i * 8) * 64]);
      async16(Bsrc + (size_t)i * 8 * 1024 + kt * 64, &Bs[(w * 32 + i * 8) * 64]);
    }
    __syncthreads();
#pragma unroll
    for (int kk = 0; kk < 2; ++kk) {
      const int kg = kk * 4 + (ln >> 4);
      hfx8 af[4], bfr[4];
#pragma unroll
      for (int mi = 0; mi < 4; ++mi) {
        int row = wr * 64 + mi * 16 + (ln & 15);
        af[mi] = *(const hfx8*)&As[row * 64 + ((kg ^ (row & 7)) * 8)];
      }
#pragma unroll
      for (int ni = 0; ni < 4; ++ni) {
        int row = wc * 64 + ni * 16 + (ln & 15);
        bfr[ni] = *(const hfx8*)&Bs[row * 64 + ((kg ^ (row & 7)) * 8)];
      }
#pragma unroll
      for (int mi = 0; mi < 4; ++mi)
#pragma unroll
        for (int ni = 0; ni < 4; ++ni)
          acc[mi][ni] = __builtin_amdgcn_mfma_f32_16x16x32_f16(af[mi], bfr[ni], acc[mi][ni], 0, 0, 0);
    }
    __syncthreads();
  }
  const int cb = n0 + wc * 64 + (ln & 15);
  const int rloc = wr * 64 + ((ln >> 4) << 2);
  if (sel == 0) {
    const int m0 = mt * 128;
#pragma unroll
    for (int mi = 0; mi < 4; ++mi)
#pragma unroll
      for (int ni = 0; ni < 4; ++ni)
#pragma unroll
        for (int j = 0; j < 4; ++j)
          Qf[(size_t)(m0 + rloc + mi * 16 + j) * 1024 + cb + ni * 16] = f2h(acc[mi][ni][j] * 0.125f);
  } else if (sel == 1) {
    // K dense into compacted rows
#pragma unroll
    for (int mi = 0; mi < 4; ++mi)
#pragma unroll
      for (int ni = 0; ni < 4; ++ni)
#pragma unroll
        for (int j = 0; j < 4; ++j)
          Kf[(size_t)(bI * 2048 + r0 + rloc + mi * 16 + j) * 1024 + cb + ni * 16] = f2h(acc[mi][ni][j]);
  } else {
    // V^T compacted: Vt[((bI*16+h2)*64+d2)][r0 + rloc + mi*16 .. +3] (usx4)
#pragma unroll
    for (int mi = 0; mi < 4; ++mi)
#pragma unroll
      for (int ni = 0; ni < 4; ++ni) {
        int c = cb + ni * 16;
        int h2 = (c >> 6) & 15, d2 = c & 63;
        usx4 pk;
#pragma unroll
        for (int j = 0; j < 4; ++j) pk[j] = f2h(acc[mi][ni][j]);
        *(usx4*)&Vt[((size_t)(bI * 16 + h2) * 64 + d2) * 2048 + r0 + rloc + mi * 16] = pk;
      }
  }
}

// O-projection fp16: C = A[4096][1024] * W^T, f32 out; m97 single-buffer
__global__ __launch_bounds__(256, 4)
void gemm_o(const unsigned short* __restrict__ A,
            const unsigned short* __restrict__ W,
            float* __restrict__ O) {
  __shared__ unsigned short As[128 * 64];
  __shared__ unsigned short Bs[128 * 64];
  const int tid = threadIdx.x;
  const int w = tid >> 6, ln = tid & 63;
  const int mt = blockIdx.x, nt = blockIdx.y;
  const int m0 = mt * 128, n0 = nt * 128;
  const int wr = w >> 1, wc = w & 1;
  fx4 acc[4][4] = {};
  const int lr = ln >> 3;
  const int scg = (ln & 7) ^ lr;
  const unsigned short* Asrc = A + (size_t)(m0 + w * 32 + lr) * 1024 + scg * 8;
  const unsigned short* Bsrc = W + (size_t)(n0 + w * 32 + lr) * 1024 + scg * 8;

  for (int kt = 0; kt < 16; ++kt) {
#pragma unroll
    for (int i = 0; i < 4; ++i) {
      async16(Asrc + (size_t)i * 8 * 1024 + kt * 64, &As[(w * 32 + i * 8) * 64]);
      async16(Bsrc + (size_t)i * 8 * 1024 + kt * 64, &Bs[(w * 32 + i * 8) * 64]);
    }
    __syncthreads();
#pragma unroll
    for (int kk = 0; kk < 2; ++kk) {
      const int kg = kk * 4 + (ln >> 4);
      hfx8 af[4], bfr[4];
#pragma unroll
      for (int mi = 0; mi < 4; ++mi) {
        int row = wr * 64 + mi * 16 + (ln & 15);
        af[mi] = *(const hfx8*)&As[row * 64 + ((kg ^ (row & 7)) * 8)];
      }
#pragma unroll
      for (int ni = 0; ni < 4; ++ni) {
        int row = wc * 64 + ni * 16 + (ln & 15);
        bfr[ni] = *(const hfx8*)&Bs[row * 64 + ((kg ^ (row & 7)) * 8)];
      }
#pragma unroll
      for (int mi = 0; mi < 4; ++mi)
#pragma unroll
        for (int ni = 0; ni < 4; ++ni)
          acc[mi][ni] = __builtin_amdgcn_mfma_f32_16x16x32_f16(af[mi], bfr[ni], acc[mi][ni], 0, 0, 0);
    }
    __syncthreads();
  }
  const int cb = n0 + wc * 64 + (ln & 15);
  const int rb = m0 + wr * 64 + ((ln >> 4) << 2);
#pragma unroll
  for (int mi = 0; mi < 4; ++mi)
#pragma unroll
    for (int ni = 0; ni < 4; ++ni)
#pragma unroll
      for (int j = 0; j < 4; ++j)
        O[(size_t)(rb + mi * 16 + j) * 1024 + cb + ni * 16] = acc[mi][ni][j];
}

// Flash attention fp16 on 32x32x16 MFMA over COMPACTED keys.
// 8-wave blocks (512 thr): waves 0-3 (group 0) process key-tiles [0, nh0),
// waves 4-7 (group 1) the rest; each group has its own SINGLE-buffered 32KB
// K/V half of LDS. 16 waves/CU (4/SIMD) to fill the softmax dependency
// bubbles. Exact flash-merge of the two partials in LDS at the end.
// Linear grid 512, XCD-chunk swizzled (512 = 8*64).
__global__ __launch_bounds__(512, 4)
void attn_fwd(const unsigned short* __restrict__ Qf,
              const unsigned short* __restrict__ Kf,
              const unsigned short* __restrict__ Vt,
              const int* __restrict__ cnt,
              unsigned short* __restrict__ Ov) {
  __shared__ __align__(16) unsigned short smem[32768];  // 64KB
  // group g: K = smem + g*16384 (16KB), V = smem + g*16384 + 8192 (16KB)
  float* obufF = (float*)smem;              // combine: 4x64x32 f32 = 32KB
  float* mlbuf = (float*)(smem + 16384);    // combine: 128 q x 2 f32 = 1KB
  unsigned short* eb = smem;                // epilogue (22.5KB), after barrier

  const int tid = threadIdx.x;
  const int w = tid >> 6, ln = tid & 63;
  const int g = w >> 2, wsub = w & 3;
  unsigned short* Ks = smem + g * 16384;
  unsigned short* Vs = Ks + 8192;
  const int bid = blockIdx.x;
  const int wg = (bid & 7) * 64 + (bid >> 3);  // XCD-chunk swizzle (bijective)
  const int qt = wg & 15, h = (wg >> 4) & 15, b = wg >> 8;
  const int l31 = ln & 31, h5 = ln >> 5;
  const int q = qt * 128 + wsub * 32 + l31;

  const int cnt_b = cnt[b];
  const int ntile = (cnt_b + 127) >> 7;
  const int nh0 = (ntile + 1) >> 1;            // group 0: [0,nh0), group 1: [nh0,ntile)

  // Q as B-fragments: lane holds Q[q][d = dc*16 + h5*8 + 0..7]
  hfx8 qb[4];
  {
    const unsigned short* qp = Qf + (size_t)(b * 2048 + q) * 1024 + h * 64 + h5 * 8;
    qb[0] = *(const hfx8*)(qp);
    qb[1] = *(const hfx8*)(qp + 16);
    qb[2] = *(const hfx8*)(qp + 32);
    qb[3] = *(const hfx8*)(qp + 48);
  }

  fx16 o0 = {}, o1 = {};
  float mrow = -INFINITY, lrow = 0.f;
  const fp16x2 one2 = { (__fp16)1.0f, (__fp16)1.0f };

  // Staging (4 waves per group): K: wave stages 32 rows; V: 16 rows.
  // Swizzle keys: K row&7 = ln>>3 ; V row&7 = (ii*4 + (ln>>4)) & 7.
#define A_STAGE(KT)                                                              \
  {                                                                              \
    _Pragma("unroll") for (int ii = 0; ii < 4; ++ii) {                           \
      int krow = wsub * 32 + ii * 8 + (ln >> 3);                                 \
      async16(Kf + ((size_t)(b * 2048 + (KT) * 128 + krow)) * 1024 + h * 64 +    \
                  (((ln & 7) ^ (ln >> 3)) * 8),                                  \
              &Ks[(wsub * 4 + ii) * 512]);                                       \
      int vswz = (ii * 4 + (ln >> 4)) & 7;                                       \
      int vrow = wsub * 16 + ii * 4 + (ln >> 4);                                 \
      async16(Vt + ((size_t)((b * 16 + h) * 64 + vrow)) * 2048 + (KT) * 128 +    \
                  (((ln & 15) ^ vswz) * 8),                                      \
              &Vs[(wsub * 4 + ii) * 512]);                                       \
    }                                                                            \
  }

  for (int i = 0; i < nh0; ++i) {
    const int t = (g ? nh0 : 0) + i;
    const bool active = t < (g ? ntile : nh0);
    if (active) A_STAGE(t);
    __syncthreads();
    if (active) {
      const bool lastt = (t == ntile - 1);

      // QK: s[kb] C[key = kb*32 + crow(reg,h5)][q = l31]; tail-mask on last tile
      fx16 sArr[4];
#pragma unroll
      for (int kb = 0; kb < 4; ++kb) {
        fx16 z = {};
        if (lastt) {
#pragma unroll
          for (int r = 0; r < 16; ++r) {
            int crow = (r & 3) + 8 * (r >> 2) + 4 * h5;
            int key = t * 128 + kb * 32 + crow;
            z[r] = (key < cnt_b) ? 0.0f : -1e30f;
          }
        }
#pragma unroll
        for (int dc = 0; dc < 4; ++dc) {
          int row = kb * 32 + l31;
          int slot = (dc * 2 + h5) ^ (l31 & 7);
          hfx8 a = *(const hfx8*)&Ks[row * 64 + slot * 8];
          z = __builtin_amdgcn_mfma_f32_32x32x16_f16(a, qb[dc], z, 0, 0, 0);
        }
        sArr[kb] = z;
      }

      // online softmax (per-q state lane-local; partner = lane^32)
      float tm = -INFINITY;
#pragma unroll
      for (int kb = 0; kb < 4; ++kb)
#pragma unroll
        for (int j = 0; j < 8; ++j)
          tm = fmaxf(fmaxf(sArr[kb][2 * j], sArr[kb][2 * j + 1]), tm);
      {
        auto t2 = __builtin_amdgcn_permlane32_swap(__float_as_uint(tm), __float_as_uint(tm), false, false);
        tm = fmaxf(__uint_as_float(t2[0]), __uint_as_float(t2[1]));
      }
      if (!__all(tm <= mrow + 8.0f)) {
        float mn = fmaxf(mrow, tm);
        float fac = exp2f((mrow - mn) * LOG2E);
        mrow = mn;
        lrow *= fac;
#pragma unroll
        for (int r = 0; r < 16; ++r) { o0[r] *= fac; o1[r] *= fac; }
      }
      const float nm2 = -mrow * LOG2E;
      float psum = 0.f;
      unsigned int pk[4][8];
#pragma unroll
      for (int kb = 0; kb < 4; ++kb) {
#pragma unroll
        for (int j = 0; j < 8; ++j) {
          float pa = exp2f(fmaf(sArr[kb][2 * j], LOG2E, nm2));
          float pb = exp2f(fmaf(sArr[kb][2 * j + 1], LOG2E, nm2));
          union { fp16x2 h; unsigned int u; } rr;
          rr.h = __builtin_amdgcn_cvt_pkrtz(pa, pb);
          pk[kb][j] = rr.u;
          psum = __builtin_amdgcn_fdot2(rr.h, one2, psum, false);
        }
      }
      {
        auto t2 = __builtin_amdgcn_permlane32_swap(__float_as_uint(psum), __float_as_uint(psum), false, false);
        psum = __uint_as_float(t2[0]) + __uint_as_float(t2[1]);
      }
      lrow += psum;

      // PV: O^T[d][q] += V^T x P^T. B-frag via permlane32_swap.
#pragma unroll
      for (int kc = 0; kc < 8; ++kc) {
        const int kbq = kc >> 1;
        const int jb = (kc & 1) * 4;
        auto r0 = __builtin_amdgcn_permlane32_swap(pk[kbq][jb], pk[kbq][jb + 2], false, false);
        auto r1 = __builtin_amdgcn_permlane32_swap(pk[kbq][jb + 1], pk[kbq][jb + 3], false, false);
        union { unsigned int u[4]; hfx8 v; } B_;
        B_.u[0] = (unsigned int)r0[0];
        B_.u[1] = (unsigned int)r1[0];
        B_.u[2] = (unsigned int)r0[1];
        B_.u[3] = (unsigned int)r1[1];
        int slot = (kc * 2 + h5) ^ (l31 & 7);
        hfx8 va0 = *(const hfx8*)&Vs[(l31) * 128 + slot * 8];
        o0 = __builtin_amdgcn_mfma_f32_32x32x16_f16(va0, B_.v, o0, 0, 0, 0);
        hfx8 va1 = *(const hfx8*)&Vs[(32 + l31) * 128 + slot * 8];
        o1 = __builtin_amdgcn_mfma_f32_32x32x16_f16(va1, B_.v, o1, 0, 0, 0);
      }
    }
    __syncthreads();
  }
#undef A_STAGE

  // ---- flash-merge of the two groups' partials (exact) ----
  // group 1 posts o (f32), m, l to LDS
  if (g == 1) {
#pragma unroll
    for (int r = 0; r < 16; ++r) {
      int d = (r & 3) + 8 * (r >> 2) + 4 * h5;
      obufF[(wsub * 64 + d) * 32 + l31] = o0[r];
      obufF[(wsub * 64 + d + 32) * 32 + l31] = o1[r];
    }
    if (h5 == 0) {
      mlbuf[(wsub * 32 + l31) * 2] = mrow;
      mlbuf[(wsub * 32 + l31) * 2 + 1] = lrow;
    }
  }
  __syncthreads();
  float inv = 0.f;
  if (g == 0) {
    float m1 = mlbuf[(wsub * 32 + l31) * 2];
    float l1 = mlbuf[(wsub * 32 + l31) * 2 + 1];
    float mN = fmaxf(mrow, m1);
    float a0 = exp2f((mrow - mN) * LOG2E);
    float a1 = exp2f((m1 - mN) * LOG2E);
    float lC = lrow * a0 + l1 * a1;
#pragma unroll
    for (int r = 0; r < 16; ++r) {
      int d = (r & 3) + 8 * (r >> 2) + 4 * h5;
      o0[r] = o0[r] * a0 + obufF[(wsub * 64 + d) * 32 + l31] * a1;
      o1[r] = o1[r] * a0 + obufF[(wsub * 64 + d + 32) * 32 + l31] * a1;
    }
    inv = 1.0f / lC;
  }
  __syncthreads();  // obuf reads done before eb overwrites

  // epilogue (group 0 only): divide, transpose via LDS (rows padded to 88 u16),
  // then all 8 waves do the coalesced store to Av[q][h*64+d]
  if (g == 0) {
    const int ql = wsub * 32 + l31;
#pragma unroll
    for (int db = 0; db < 2; ++db) {
#pragma unroll
      for (int r4 = 0; r4 < 4; ++r4) {
        float v0 = (db ? o1[4 * r4] : o0[4 * r4]) * inv;
        float v1 = (db ? o1[4 * r4 + 1] : o0[4 * r4 + 1]) * inv;
        float v2 = (db ? o1[4 * r4 + 2] : o0[4 * r4 + 2]) * inv;
        float v3 = (db ? o1[4 * r4 + 3] : o0[4 * r4 + 3]) * inv;
        union { fp16x2 h; unsigned int u; } pa_, pb_;
        pa_.h = __builtin_amdgcn_cvt_pkrtz(v0, v1);
        pb_.h = __builtin_amdgcn_cvt_pkrtz(v2, v3);
        ux2 tw; tw[0] = pa_.u; tw[1] = pb_.u;
        int d_base = db * 32 + 8 * r4 + 4 * h5;
        *(ux2*)&eb[ql * 88 + d_base] = tw;
      }
    }
  }
  __syncthreads();
#pragma unroll
  for (int pass = 0; pass < 2; ++pass) {
    int idx = pass * 512 + tid;
    int qq = idx >> 3, slot = idx & 7;
    usx8 vv = *(const usx8*)&eb[qq * 88 + slot * 8];
    *(usx8*)&Ov[(size_t)(b * 2048 + qt * 128 + qq) * 1024 + h * 64 + slot * 8] = vv;
  }
}

// out = LayerNorm(h + attn_out) * g + b ; one block per row
__global__ __launch_bounds__(256)
void lnk(const float* __restrict__ h, const float* __restrict__ ao,
         const float* __restrict__ g, const float* __restrict__ bb,
         float* __restrict__ out) {
  const int row = blockIdx.x;
  const int tid = threadIdx.x;
  const size_t base = (size_t)row * 1024 + tid * 4;
  fx4 x = *(const fx4*)(h + base);
  fx4 a = *(const fx4*)(ao + base);
  x = x + a;
  float s = x[0] + x[1] + x[2] + x[3];
  float q = x[0] * x[0] + x[1] * x[1] + x[2] * x[2] + x[3] * x[3];
#pragma unroll
  for (int mm = 1; mm < 64; mm <<= 1) {
    s += __shfl_xor(s, mm);
    q += __shfl_xor(q, mm);
  }
  __shared__ float rs[4], rq[4];
  if ((tid & 63) == 0) { rs[tid >> 6] = s; rq[tid >> 6] = q; }
  __syncthreads();
  s = rs[0] + rs[1] + rs[2] + rs[3];
  q = rq[0] + rq[1] + rq[2] + rq[3];
  float mu = s * (1.0f / 1024.0f);
  float var = q * (1.0f / 1024.0f) - mu * mu;
  float rstd = rsqrtf(var + 1e-5f);
  fx4 gg = *(const fx4*)(g + tid * 4);
  fx4 bv = *(const fx4*)(bb + tid * 4);
  fx4 ov;
#pragma unroll
  for (int k = 0; k < 4; ++k) ov[k] = (x[k] - mu) * rstd * gg[k] + bv[k];
  *(fx4*)(out + base) = ov;
}

extern "C" void kernel_launch(void* const* d_in, const int* in_sizes, int n_in,
                              void* d_out, int out_size, void* d_ws, size_t ws_size,
                              hipStream_t stream) {
  const float* h = (const float*)d_in[0];
  const int* msk = (const int*)d_in[1];
  const float* qw = (const float*)d_in[2];
  const float* kw = (const float*)d_in[3];
  const float* vw = (const float*)d_in[4];
  const float* ow = (const float*)d_in[5];
  const float* lng = (const float*)d_in[6];
  const float* lnb = (const float*)d_in[7];
  float* out = (float*)d_out;
  char* ws = (char*)d_ws;

  const size_t MB = 1u << 20;
  unsigned short* h16 = (unsigned short*)(ws + 0 * MB);   // 8 MB
  unsigned short* w16q = (unsigned short*)(ws + 8 * MB);  // 2 MB
  unsigned short* w16k = (unsigned short*)(ws + 10 * MB); // 2 MB
  unsigned short* w16v = (unsigned short*)(ws + 12 * MB); // 2 MB
  unsigned short* w16o = (unsigned short*)(ws + 14 * MB); // 2 MB
  unsigned short* Qf  = (unsigned short*)(ws + 16 * MB);  // 8 MB
  unsigned short* Kf  = (unsigned short*)(ws + 24 * MB);  // 8 MB
  unsigned short* Vtb = (unsigned short*)(ws + 32 * MB);  // 8 MB
  unsigned short* Av  = (unsigned short*)(ws + 40 * MB);  // 8 MB
  float* Ao = (float*)(ws + 48 * MB);                     // 16 MB
  // src/cnt live in the Ao region (read by gemm_qkv/attn, both before gemm_o)
  int* srcIdx = (int*)(ws + 48 * MB);                     // 16 KB
  int* cnt    = (int*)(ws + 48 * MB + 16384);             // 8 B

  cvth<<<dim3(4096), 256, 0, stream>>>(h, h16);
  cvtw<<<dim3(1024, 4), 256, 0, stream>>>(qw, kw, vw, ow, w16q, w16k, w16v, w16o);
  maskscan<<<dim3(2), 256, 0, stream>>>(msk, srcIdx, cnt);

  gemm_qkv<<<dim3(768), 256, 0, stream>>>(h16, w16q, w16k, w16v, srcIdx, cnt, Qf, Kf, Vtb);
  attn_fwd<<<dim3(512), 512, 0, stream>>>(Qf, Kf, Vtb, cnt, Av);
  gemm_o<<<dim3(32, 8), 256, 0, stream>>>(Av, w16o, Ao);
  lnk<<<dim3(4096), 256, 0, stream>>>(h, Ao, lng, lnb, out);
}

// Round 20
// 110.119 us; speedup vs baseline: 1.1785x; 1.1785x over previous
//
#include <hip/hip_runtime.h>
#include <hip/hip_bf16.h>

typedef __attribute__((ext_vector_type(8))) _Float16 hfx8;
typedef __attribute__((ext_vector_type(16))) float fx16;
typedef __attribute__((ext_vector_type(2))) __fp16 fp16x2;
typedef __attribute__((ext_vector_type(4))) float fx4;
typedef __attribute__((ext_vector_type(4))) unsigned short usx4;
typedef __attribute__((ext_vector_type(8))) unsigned short usx8;
typedef __attribute__((ext_vector_type(2))) unsigned int ux2;

#define LOG2E 1.44269504f

__device__ __forceinline__ unsigned short f2h(float f) {
  union { _Float16 h; unsigned short u; } c;
  c.h = (_Float16)f;
  return c.u;
}

__device__ __forceinline__ void async16(const void* g, void* l) {
  __builtin_amdgcn_global_load_lds(
      (const __attribute__((address_space(1))) void*)g,
      (__attribute__((address_space(3))) void*)l, 16, 0, 0);
}

// Fused prep: blocks 0-1 = per-batch mask scan; blocks 2..4097 = h f32->fp16;
// blocks 4098..8193 = weights f32->fp16 (qw scaled by ATT_SCALE, exact exp shift).
__global__ __launch_bounds__(256)
void prep(const float* __restrict__ h, const float* __restrict__ qw,
          const float* __restrict__ kw, const float* __restrict__ vw,
          const float* __restrict__ ow, const int* __restrict__ mask,
          unsigned short* __restrict__ h16, unsigned short* __restrict__ w16q,
          unsigned short* __restrict__ w16k, unsigned short* __restrict__ w16v,
          unsigned short* __restrict__ w16o,
          int* __restrict__ src, int* __restrict__ cnt) {
  const int tid = threadIdx.x;
  const int bid = blockIdx.x;
  if (bid < 2) {
    // ---- maskscan ----
    const int b = bid;
    const int base = b * 2048 + tid * 8;
    int m[8];
    int s = 0;
#pragma unroll
    for (int e = 0; e < 8; ++e) { m[e] = mask[base + e] ? 1 : 0; s += m[e]; }
    const int lane = tid & 63, wv = tid >> 6;
    int inc = s;
#pragma unroll
    for (int off = 1; off < 64; off <<= 1) {
      int t = __shfl_up(inc, off);
      if (lane >= off) inc += t;
    }
    __shared__ int wsum[4];
    if (lane == 63) wsum[wv] = inc;
    __syncthreads();
    int wvoff = 0;
#pragma unroll
    for (int k = 0; k < 4; ++k)
      if (k < wv) wvoff += wsum[k];
    int run = wvoff + inc - s;  // exclusive prefix (in-batch)
#pragma unroll
    for (int e = 0; e < 8; ++e) {
      if (m[e]) { src[b * 2048 + run] = tid * 8 + e; ++run; }
    }
    if (tid == 255) cnt[b] = run;
    return;
  }
  // ---- f32 -> fp16 convert, 1024 elements per block ----
  int cb = bid - 2;
  const float* sp;
  unsigned short* dp;
  float sc = 1.0f;
  int idx;
  if (cb < 4096) {
    sp = h; dp = h16; idx = cb;
  } else {
    int r = cb - 4096;
    int wi = r >> 10;
    idx = r & 1023;
    if (wi == 0)      { sp = qw; dp = w16q; sc = 0.125f; }
    else if (wi == 1) { sp = kw; dp = w16k; }
    else if (wi == 2) { sp = vw; dp = w16v; }
    else              { sp = ow; dp = w16o; }
  }
  int i = (idx * 256 + tid) * 4;
  fx4 v = *(const fx4*)(sp + i);
  usx4 o;
  o[0] = f2h(v[0] * sc); o[1] = f2h(v[1] * sc);
  o[2] = f2h(v[2] * sc); o[3] = f2h(v[3] * sc);
  *(usx4*)(dp + i) = o;
}

// QKV projection fp16. Linear grid 768, XCD-chunk swizzled (768 = 8*96).
// m97-style SINGLE-buffered LDS (32 KB).
// sel=0: Q dense (w16q pre-scaled by ATT_SCALE), mt 0..31.
// sel=1/2: K/V over COMPACTED rows via src[] gather; early-exit past cnt.
__global__ __launch_bounds__(256, 4)
void gemm_qkv(const unsigned short* __restrict__ A,
              const unsigned short* __restrict__ Wq,
              const unsigned short* __restrict__ Wk,
              const unsigned short* __restrict__ Wv,
              const int* __restrict__ src, const int* __restrict__ cnt,
              unsigned short* __restrict__ Qf, unsigned short* __restrict__ Kf,
              unsigned short* __restrict__ Vt) {
  __shared__ unsigned short As[128 * 64];
  __shared__ unsigned short Bs[128 * 64];
  const int tid = threadIdx.x;
  const int w = tid >> 6, ln = tid & 63;
  const int bid = blockIdx.x;
  const int wg = (bid & 7) * 96 + (bid >> 3);  // XCD-chunk swizzle (bijective)
  const int mt = wg & 31;
  const int by = wg >> 5;
  const int sel = by >> 3;
  const int nt = by & 7;
  const unsigned short* W = (sel == 0) ? Wq : ((sel == 1) ? Wk : Wv);
  const int n0 = nt * 128;
  const int wr = w >> 1, wc = w & 1;

  const int lr = ln >> 3;
  const int scg = (ln & 7) ^ lr;

  // A-row source pointers (block-constant per lane)
  const int bI = mt >> 4;
  const int r0 = (mt & 15) * 128;
  int cnt_b = 0;
  const unsigned short* Arow[4];
  if (sel == 0) {
    const int m0 = mt * 128;
#pragma unroll
    for (int ii = 0; ii < 4; ++ii)
      Arow[ii] = A + (size_t)(m0 + w * 32 + ii * 8 + lr) * 1024 + scg * 8;
  } else {
    cnt_b = cnt[bI];
    if (r0 >= cnt_b) return;
#pragma unroll
    for (int ii = 0; ii < 4; ++ii) {
      int r = r0 + w * 32 + ii * 8 + lr;
      r = (r < cnt_b) ? r : (cnt_b - 1);
      Arow[ii] = A + (size_t)(bI * 2048 + src[bI * 2048 + r]) * 1024 + scg * 8;
    }
  }
  const unsigned short* Bsrc = W + (size_t)(n0 + w * 32 + lr) * 1024 + scg * 8;

  fx4 acc[4][4] = {};

  for (int kt = 0; kt < 16; ++kt) {
#pragma unroll
    for (int i = 0; i < 4; ++i) {
      async16(Arow[i] + kt * 64, &As[(w * 32 + i * 8) * 64]);
      async16(Bsrc + (size_t)i * 8 * 1024 + kt * 64, &Bs[(w * 32 + i * 8) * 64]);
    }
    __syncthreads();
#pragma unroll
    for (int kk = 0; kk < 2; ++kk) {
      const int kg = kk * 4 + (ln >> 4);
      hfx8 af[4], bfr[4];
#pragma unroll
      for (int mi = 0; mi < 4; ++mi) {
        int row = wr * 64 + mi * 16 + (ln & 15);
        af[mi] = *(const hfx8*)&As[row * 64 + ((kg ^ (row & 7)) * 8)];
      }
#pragma unroll
      for (int ni = 0; ni < 4; ++ni) {
        int row = wc * 64 + ni * 16 + (ln & 15);
        bfr[ni] = *(const hfx8*)&Bs[row * 64 + ((kg ^ (row & 7)) * 8)];
      }
#pragma unroll
      for (int mi = 0; mi < 4; ++mi)
#pragma unroll
        for (int ni = 0; ni < 4; ++ni)
          acc[mi][ni] = __builtin_amdgcn_mfma_f32_16x16x32_f16(af[mi], bfr[ni], acc[mi][ni], 0, 0, 0);
    }
    __syncthreads();
  }
  const int cb = n0 + wc * 64 + (ln & 15);
  const int rloc = wr * 64 + ((ln >> 4) << 2);
  if (sel == 0) {
    const int m0 = mt * 128;
#pragma unroll
    for (int mi = 0; mi < 4; ++mi)
#pragma unroll
      for (int ni = 0; ni < 4; ++ni)
#pragma unroll
        for (int j = 0; j < 4; ++j)
          Qf[(size_t)(m0 + rloc + mi * 16 + j) * 1024 + cb + ni * 16] = f2h(acc[mi][ni][j]);
  } else if (sel == 1) {
    // K dense into compacted rows
#pragma unroll
    for (int mi = 0; mi < 4; ++mi)
#pragma unroll
      for (int ni = 0; ni < 4; ++ni)
#pragma unroll
        for (int j = 0; j < 4; ++j)
          Kf[(size_t)(bI * 2048 + r0 + rloc + mi * 16 + j) * 1024 + cb + ni * 16] = f2h(acc[mi][ni][j]);
  } else {
    // V^T compacted: Vt[((bI*16+h2)*64+d2)][r0 + rloc + mi*16 .. +3] (usx4)
#pragma unroll
    for (int mi = 0; mi < 4; ++mi)
#pragma unroll
      for (int ni = 0; ni < 4; ++ni) {
        int c = cb + ni * 16;
        int h2 = (c >> 6) & 15, d2 = c & 63;
        usx4 pk;
#pragma unroll
        for (int j = 0; j < 4; ++j) pk[j] = f2h(acc[mi][ni][j]);
        *(usx4*)&Vt[((size_t)(bI * 16 + h2) * 64 + d2) * 2048 + r0 + rloc + mi * 16] = pk;
      }
  }
}

// O-projection fp16: C = A[4096][1024] * W^T, f32 out; m97 single-buffer
__global__ __launch_bounds__(256, 4)
void gemm_o(const unsigned short* __restrict__ A,
            const unsigned short* __restrict__ W,
            float* __restrict__ O) {
  __shared__ unsigned short As[128 * 64];
  __shared__ unsigned short Bs[128 * 64];
  const int tid = threadIdx.x;
  const int w = tid >> 6, ln = tid & 63;
  const int mt = blockIdx.x, nt = blockIdx.y;
  const int m0 = mt * 128, n0 = nt * 128;
  const int wr = w >> 1, wc = w & 1;
  fx4 acc[4][4] = {};
  const int lr = ln >> 3;
  const int scg = (ln & 7) ^ lr;
  const unsigned short* Asrc = A + (size_t)(m0 + w * 32 + lr) * 1024 + scg * 8;
  const unsigned short* Bsrc = W + (size_t)(n0 + w * 32 + lr) * 1024 + scg * 8;

  for (int kt = 0; kt < 16; ++kt) {
#pragma unroll
    for (int i = 0; i < 4; ++i) {
      async16(Asrc + (size_t)i * 8 * 1024 + kt * 64, &As[(w * 32 + i * 8) * 64]);
      async16(Bsrc + (size_t)i * 8 * 1024 + kt * 64, &Bs[(w * 32 + i * 8) * 64]);
    }
    __syncthreads();
#pragma unroll
    for (int kk = 0; kk < 2; ++kk) {
      const int kg = kk * 4 + (ln >> 4);
      hfx8 af[4], bfr[4];
#pragma unroll
      for (int mi = 0; mi < 4; ++mi) {
        int row = wr * 64 + mi * 16 + (ln & 15);
        af[mi] = *(const hfx8*)&As[row * 64 + ((kg ^ (row & 7)) * 8)];
      }
#pragma unroll
      for (int ni = 0; ni < 4; ++ni) {
        int row = wc * 64 + ni * 16 + (ln & 15);
        bfr[ni] = *(const hfx8*)&Bs[row * 64 + ((kg ^ (row & 7)) * 8)];
      }
#pragma unroll
      for (int mi = 0; mi < 4; ++mi)
#pragma unroll
        for (int ni = 0; ni < 4; ++ni)
          acc[mi][ni] = __builtin_amdgcn_mfma_f32_16x16x32_f16(af[mi], bfr[ni], acc[mi][ni], 0, 0, 0);
    }
    __syncthreads();
  }
  const int cb = n0 + wc * 64 + (ln & 15);
  const int rb = m0 + wr * 64 + ((ln >> 4) << 2);
#pragma unroll
  for (int mi = 0; mi < 4; ++mi)
#pragma unroll
    for (int ni = 0; ni < 4; ++ni)
#pragma unroll
      for (int j = 0; j < 4; ++j)
        O[(size_t)(rb + mi * 16 + j) * 1024 + cb + ni * 16] = acc[mi][ni][j];
}

// Flash attention fp16 on 32x32x16 MFMA over COMPACTED keys.
// Grid 512 (2 blocks/CU), DOUBLE-buffered K/V, 4 waves (R16/R18-proven optimum).
// Cross-half exchange via __builtin_amdgcn_permlane32_swap (VALU pipe).
__global__ __launch_bounds__(256, 2)
void attn_fwd(const unsigned short* __restrict__ Qf,
              const unsigned short* __restrict__ Kf,
              const unsigned short* __restrict__ Vt,
              const int* __restrict__ cnt,
              unsigned short* __restrict__ Ov) {
  __shared__ __align__(16) unsigned short smem[32768];  // 64KB
  unsigned short (*Ks)[8192] = (unsigned short (*)[8192])(smem);          // 2 x 16KB
  unsigned short (*Vs)[8192] = (unsigned short (*)[8192])(smem + 16384);  // 2 x 16KB
  unsigned short* eb = smem;                                              // epilogue reuse

  const int tid = threadIdx.x;
  const int w = tid >> 6, ln = tid & 63;
  const int bid = blockIdx.x;
  const int wg = (bid & 7) * 64 + (bid >> 3);  // XCD-chunk swizzle (bijective)
  const int qt = wg & 15, h = (wg >> 4) & 15, b = wg >> 8;
  const int l31 = ln & 31, h5 = ln >> 5;
  const int q = qt * 128 + w * 32 + l31;

  const int cnt_b = cnt[b];
  const int ntile = (cnt_b + 127) >> 7;

  // Q as B-fragments: lane holds Q[q][d = dc*16 + h5*8 + 0..7]
  hfx8 qb[4];
  {
    const unsigned short* qp = Qf + (size_t)(b * 2048 + q) * 1024 + h * 64 + h5 * 8;
    qb[0] = *(const hfx8*)(qp);
    qb[1] = *(const hfx8*)(qp + 16);
    qb[2] = *(const hfx8*)(qp + 32);
    qb[3] = *(const hfx8*)(qp + 48);
  }

  fx16 o0 = {}, o1 = {};
  float mrow = -INFINITY, lrow = 0.f;
  const fp16x2 one2 = { (__fp16)1.0f, (__fp16)1.0f };

  // Staging (4 waves): K: wave stages 32 rows (4 chunks of 8 rows x 64d);
  //                    V: wave stages 16 rows (4 chunks of 4 rows x 128s).
  // Swizzle keys: K row&7 = ln>>3 ; V row&7 = (ii*4 + (ln>>4)) & 7.
#define A_STAGE(KT, BI)                                                          \
  {                                                                              \
    _Pragma("unroll") for (int ii = 0; ii < 4; ++ii) {                           \
      int krow = w * 32 + ii * 8 + (ln >> 3);                                    \
      async16(Kf + ((size_t)(b * 2048 + (KT) * 128 + krow)) * 1024 + h * 64 +    \
                  (((ln & 7) ^ (ln >> 3)) * 8),                                  \
              &Ks[BI][(w * 4 + ii) * 512]);                                      \
      int vswz = (ii * 4 + (ln >> 4)) & 7;                                       \
      int vrow = w * 16 + ii * 4 + (ln >> 4);                                    \
      async16(Vt + ((size_t)((b * 16 + h) * 64 + vrow)) * 2048 + (KT) * 128 +    \
                  (((ln & 15) ^ vswz) * 8),                                      \
              &Vs[BI][(w * 4 + ii) * 512]);                                      \
    }                                                                            \
  }

  A_STAGE(0, 0);
  for (int kt = 0; kt < ntile; ++kt) {
    const int cur = kt & 1;
    __syncthreads();
    if (kt + 1 < ntile) A_STAGE(kt + 1, cur ^ 1);
    const bool lastt = (kt == ntile - 1);

    // QK: s[kb] C[key = kb*32 + crow(reg,h5)][q = l31]; C-init 0, or tail-mask on last tile
    fx16 sArr[4];
#pragma unroll
    for (int kb = 0; kb < 4; ++kb) {
      fx16 z = {};
      if (lastt) {
#pragma unroll
        for (int r = 0; r < 16; ++r) {
          int crow = (r & 3) + 8 * (r >> 2) + 4 * h5;
          int key = kt * 128 + kb * 32 + crow;
          z[r] = (key < cnt_b) ? 0.0f : -1e30f;
        }
      }
#pragma unroll
      for (int dc = 0; dc < 4; ++dc) {
        int row = kb * 32 + l31;
        int slot = (dc * 2 + h5) ^ (l31 & 7);
        hfx8 a = *(const hfx8*)&Ks[cur][row * 64 + slot * 8];
        z = __builtin_amdgcn_mfma_f32_32x32x16_f16(a, qb[dc], z, 0, 0, 0);
      }
      sArr[kb] = z;
    }

    // online softmax (per-q state lane-local; partner = lane^32 via permlane swap).
    float tm = -INFINITY;
#pragma unroll
    for (int kb = 0; kb < 4; ++kb)
#pragma unroll
      for (int j = 0; j < 8; ++j)
        tm = fmaxf(fmaxf(sArr[kb][2 * j], sArr[kb][2 * j + 1]), tm);
    {
      auto t = __builtin_amdgcn_permlane32_swap(__float_as_uint(tm), __float_as_uint(tm), false, false);
      tm = fmaxf(__uint_as_float(t[0]), __uint_as_float(t[1]));
    }
    if (!__all(tm <= mrow + 8.0f)) {
      float mn = fmaxf(mrow, tm);
      float fac = exp2f((mrow - mn) * LOG2E);
      mrow = mn;
      lrow *= fac;
#pragma unroll
      for (int r = 0; r < 16; ++r) { o0[r] *= fac; o1[r] *= fac; }
    }
    const float nm2 = -mrow * LOG2E;
    float psum = 0.f;
    unsigned int pk[4][8];
#pragma unroll
    for (int kb = 0; kb < 4; ++kb) {
#pragma unroll
      for (int j = 0; j < 8; ++j) {
        float pa = exp2f(fmaf(sArr[kb][2 * j], LOG2E, nm2));
        float pb = exp2f(fmaf(sArr[kb][2 * j + 1], LOG2E, nm2));
        union { fp16x2 h; unsigned int u; } rr;
        rr.h = __builtin_amdgcn_cvt_pkrtz(pa, pb);
        pk[kb][j] = rr.u;
        psum = __builtin_amdgcn_fdot2(rr.h, one2, psum, false);
      }
    }
    {
      auto t = __builtin_amdgcn_permlane32_swap(__float_as_uint(psum), __float_as_uint(psum), false, false);
      psum = __uint_as_float(t[0]) + __uint_as_float(t[1]);
    }
    lrow += psum;

    // PV: O^T[d][q] += V^T x P^T. B-frag via permlane32_swap.
#pragma unroll
    for (int kc = 0; kc < 8; ++kc) {
      const int kbq = kc >> 1;
      const int jb = (kc & 1) * 4;
      auto r0 = __builtin_amdgcn_permlane32_swap(pk[kbq][jb], pk[kbq][jb + 2], false, false);
      auto r1 = __builtin_amdgcn_permlane32_swap(pk[kbq][jb + 1], pk[kbq][jb + 3], false, false);
      union { unsigned int u[4]; hfx8 v; } B_;
      B_.u[0] = (unsigned int)r0[0];
      B_.u[1] = (unsigned int)r1[0];
      B_.u[2] = (unsigned int)r0[1];
      B_.u[3] = (unsigned int)r1[1];
      int slot = (kc * 2 + h5) ^ (l31 & 7);
      hfx8 va0 = *(const hfx8*)&Vs[cur][(l31) * 128 + slot * 8];
      o0 = __builtin_amdgcn_mfma_f32_32x32x16_f16(va0, B_.v, o0, 0, 0, 0);
      hfx8 va1 = *(const hfx8*)&Vs[cur][(32 + l31) * 128 + slot * 8];
      o1 = __builtin_amdgcn_mfma_f32_32x32x16_f16(va1, B_.v, o1, 0, 0, 0);
    }
  }
#undef A_STAGE

  // epilogue: divide, transpose via LDS (rows padded to 88 u16 = 176B, 16B-aligned),
  // coalesced store to Av[q][h*64+d]
  __syncthreads();  // all waves done reading K/V LDS before overwrite
  float inv = 1.0f / lrow;
  const int ql = w * 32 + l31;
#pragma unroll
  for (int db = 0; db < 2; ++db) {
#pragma unroll
    for (int r4 = 0; r4 < 4; ++r4) {
      float v0 = (db ? o1[4 * r4] : o0[4 * r4]) * inv;
      float v1 = (db ? o1[4 * r4 + 1] : o0[4 * r4 + 1]) * inv;
      float v2 = (db ? o1[4 * r4 + 2] : o0[4 * r4 + 2]) * inv;
      float v3 = (db ? o1[4 * r4 + 3] : o0[4 * r4 + 3]) * inv;
      union { fp16x2 h; unsigned int u; } pa_, pb_;
      pa_.h = __builtin_amdgcn_cvt_pkrtz(v0, v1);
      pb_.h = __builtin_amdgcn_cvt_pkrtz(v2, v3);
      ux2 tw; tw[0] = pa_.u; tw[1] = pb_.u;
      int d_base = db * 32 + 8 * r4 + 4 * h5;
      *(ux2*)&eb[ql * 88 + d_base] = tw;
    }
  }
  __syncthreads();
#pragma unroll
  for (int pass = 0; pass < 4; ++pass) {
    int idx = pass * 256 + tid;
    int qq = idx >> 3, slot = idx & 7;
    usx8 vv = *(const usx8*)&eb[qq * 88 + slot * 8];
    *(usx8*)&Ov[(size_t)(b * 2048 + qt * 128 + qq) * 1024 + h * 64 + slot * 8] = vv;
  }
}

// out = LayerNorm(h + attn_out) * g + b ; one block per row
__global__ __launch_bounds__(256)
void lnk(const float* __restrict__ h, const float* __restrict__ ao,
         const float* __restrict__ g, const float* __restrict__ bb,
         float* __restrict__ out) {
  const int row = blockIdx.x;
  const int tid = threadIdx.x;
  const size_t base = (size_t)row * 1024 + tid * 4;
  fx4 x = *(const fx4*)(h + base);
  fx4 a = *(const fx4*)(ao + base);
  x = x + a;
  float s = x[0] + x[1] + x[2] + x[3];
  float q = x[0] * x[0] + x[1] * x[1] + x[2] * x[2] + x[3] * x[3];
#pragma unroll
  for (int mm = 1; mm < 64; mm <<= 1) {
    s += __shfl_xor(s, mm);
    q += __shfl_xor(q, mm);
  }
  __shared__ float rs[4], rq[4];
  if ((tid & 63) == 0) { rs[tid >> 6] = s; rq[tid >> 6] = q; }
  __syncthreads();
  s = rs[0] + rs[1] + rs[2] + rs[3];
  q = rq[0] + rq[1] + rq[2] + rq[3];
  float mu = s * (1.0f / 1024.0f);
  float var = q * (1.0f / 1024.0f) - mu * mu;
  float rstd = rsqrtf(var + 1e-5f);
  fx4 gg = *(const fx4*)(g + tid * 4);
  fx4 bv = *(const fx4*)(bb + tid * 4);
  fx4 ov;
#pragma unroll
  for (int k = 0; k < 4; ++k) ov[k] = (x[k] - mu) * rstd * gg[k] + bv[k];
  *(fx4*)(out + base) = ov;
}

extern "C" void kernel_launch(void* const* d_in, const int* in_sizes, int n_in,
                              void* d_out, int out_size, void* d_ws, size_t ws_size,
                              hipStream_t stream) {
  const float* h = (const float*)d_in[0];
  const int* msk = (const int*)d_in[1];
  const float* qw = (const float*)d_in[2];
  const float* kw = (const float*)d_in[3];
  const float* vw = (const float*)d_in[4];
  const float* ow = (const float*)d_in[5];
  const float* lng = (const float*)d_in[6];
  const float* lnb = (const float*)d_in[7];
  float* out = (float*)d_out;
  char* ws = (char*)d_ws;

  const size_t MB = 1u << 20;
  unsigned short* h16 = (unsigned short*)(ws + 0 * MB);   // 8 MB
  unsigned short* w16q = (unsigned short*)(ws + 8 * MB);  // 2 MB
  unsigned short* w16k = (unsigned short*)(ws + 10 * MB); // 2 MB
  unsigned short* w16v = (unsigned short*)(ws + 12 * MB); // 2 MB
  unsigned short* w16o = (unsigned short*)(ws + 14 * MB); // 2 MB
  unsigned short* Qf  = (unsigned short*)(ws + 16 * MB);  // 8 MB
  unsigned short* Kf  = (unsigned short*)(ws + 24 * MB);  // 8 MB
  unsigned short* Vtb = (unsigned short*)(ws + 32 * MB);  // 8 MB
  unsigned short* Av  = (unsigned short*)(ws + 40 * MB);  // 8 MB
  float* Ao = (float*)(ws + 48 * MB);                     // 16 MB
  // src/cnt live in the Ao region (read by gemm_qkv/attn, both before gemm_o)
  int* srcIdx = (int*)(ws + 48 * MB);                     // 16 KB
  int* cnt    = (int*)(ws + 48 * MB + 16384);             // 8 B

  prep<<<dim3(8194), 256, 0, stream>>>(h, qw, kw, vw, ow, msk,
                                       h16, w16q, w16k, w16v, w16o, srcIdx, cnt);
  gemm_qkv<<<dim3(768), 256, 0, stream>>>(h16, w16q, w16k, w16v, srcIdx, cnt, Qf, Kf, Vtb);
  attn_fwd<<<dim3(512), 256, 0, stream>>>(Qf, Kf, Vtb, cnt, Av);
  gemm_o<<<dim3(32, 8), 256, 0, stream>>>(Av, w16o, Ao);
  lnk<<<dim3(4096), 256, 0, stream>>>(h, Ao, lng, lnb, out);
}

// Round 21
// 109.876 us; speedup vs baseline: 1.1811x; 1.0022x over previous
//
#include <hip/hip_runtime.h>
#include <hip/hip_bf16.h>

typedef __attribute__((ext_vector_type(8))) _Float16 hfx8;
typedef __attribute__((ext_vector_type(16))) float fx16;
typedef __attribute__((ext_vector_type(2))) __fp16 fp16x2;
typedef __attribute__((ext_vector_type(4))) float fx4;
typedef __attribute__((ext_vector_type(4))) unsigned short usx4;
typedef __attribute__((ext_vector_type(8))) unsigned short usx8;
typedef __attribute__((ext_vector_type(2))) unsigned int ux2;

#define LOG2E 1.44269504f

__device__ __forceinline__ unsigned short f2h(float f) {
  union { _Float16 h; unsigned short u; } c;
  c.h = (_Float16)f;
  return c.u;
}

__device__ __forceinline__ void async16(const void* g, void* l) {
  __builtin_amdgcn_global_load_lds(
      (const __attribute__((address_space(1))) void*)g,
      (__attribute__((address_space(3))) void*)l, 16, 0, 0);
}

// Fused prep: blocks 0-1 = per-batch mask scan; blocks 2..4097 = h f32->fp16;
// blocks 4098..8193 = weights f32->fp16 (qw scaled by ATT_SCALE).
__global__ __launch_bounds__(256)
void prep(const float* __restrict__ h, const float* __restrict__ qw,
          const float* __restrict__ kw, const float* __restrict__ vw,
          const float* __restrict__ ow, const int* __restrict__ mask,
          unsigned short* __restrict__ h16, unsigned short* __restrict__ w16q,
          unsigned short* __restrict__ w16k, unsigned short* __restrict__ w16v,
          unsigned short* __restrict__ w16o,
          int* __restrict__ src, int* __restrict__ cnt) {
  const int tid = threadIdx.x;
  const int bid = blockIdx.x;
  if (bid < 2) {
    // ---- maskscan ----
    const int b = bid;
    const int base = b * 2048 + tid * 8;
    int m[8];
    int s = 0;
#pragma unroll
    for (int e = 0; e < 8; ++e) { m[e] = mask[base + e] ? 1 : 0; s += m[e]; }
    const int lane = tid & 63, wv = tid >> 6;
    int inc = s;
#pragma unroll
    for (int off = 1; off < 64; off <<= 1) {
      int t = __shfl_up(inc, off);
      if (lane >= off) inc += t;
    }
    __shared__ int wsum[4];
    if (lane == 63) wsum[wv] = inc;
    __syncthreads();
    int wvoff = 0;
#pragma unroll
    for (int k = 0; k < 4; ++k)
      if (k < wv) wvoff += wsum[k];
    int run = wvoff + inc - s;  // exclusive prefix (in-batch)
#pragma unroll
    for (int e = 0; e < 8; ++e) {
      if (m[e]) { src[b * 2048 + run] = tid * 8 + e; ++run; }
    }
    if (tid == 255) cnt[b] = run;
    return;
  }
  // ---- f32 -> fp16 convert, 1024 elements per block ----
  int cb = bid - 2;
  const float* sp;
  unsigned short* dp;
  float sc = 1.0f;
  int idx;
  if (cb < 4096) {
    sp = h; dp = h16; idx = cb;
  } else {
    int r = cb - 4096;
    int wi = r >> 10;
    idx = r & 1023;
    if (wi == 0)      { sp = qw; dp = w16q; sc = 0.125f; }
    else if (wi == 1) { sp = kw; dp = w16k; }
    else if (wi == 2) { sp = vw; dp = w16v; }
    else              { sp = ow; dp = w16o; }
  }
  int i = (idx * 256 + tid) * 4;
  fx4 v = *(const fx4*)(sp + i);
  usx4 o;
  o[0] = f2h(v[0] * sc); o[1] = f2h(v[1] * sc);
  o[2] = f2h(v[2] * sc); o[3] = f2h(v[3] * sc);
  *(usx4*)(dp + i) = o;
}

// QKV projection fp16. Linear grid 768, XCD-chunk swizzled (768 = 8*96).
// m97-style SINGLE-buffered LDS (grid 768 -> ~3 blocks/CU, cross-block overlap).
// sel=0: Q dense (w16q pre-scaled by ATT_SCALE), mt 0..31.
// sel=1/2: K/V over COMPACTED rows via src[] gather; early-exit past cnt.
__global__ __launch_bounds__(256, 4)
void gemm_qkv(const unsigned short* __restrict__ A,
              const unsigned short* __restrict__ Wq,
              const unsigned short* __restrict__ Wk,
              const unsigned short* __restrict__ Wv,
              const int* __restrict__ src, const int* __restrict__ cnt,
              unsigned short* __restrict__ Qf, unsigned short* __restrict__ Kf,
              unsigned short* __restrict__ Vt) {
  __shared__ unsigned short As[128 * 64];
  __shared__ unsigned short Bs[128 * 64];
  const int tid = threadIdx.x;
  const int w = tid >> 6, ln = tid & 63;
  const int bid = blockIdx.x;
  const int wg = (bid & 7) * 96 + (bid >> 3);  // XCD-chunk swizzle (bijective)
  const int mt = wg & 31;
  const int by = wg >> 5;
  const int sel = by >> 3;
  const int nt = by & 7;
  const unsigned short* W = (sel == 0) ? Wq : ((sel == 1) ? Wk : Wv);
  const int n0 = nt * 128;
  const int wr = w >> 1, wc = w & 1;

  const int lr = ln >> 3;
  const int scg = (ln & 7) ^ lr;

  // A-row source pointers (block-constant per lane)
  const int bI = mt >> 4;
  const int r0 = (mt & 15) * 128;
  int cnt_b = 0;
  const unsigned short* Arow[4];
  if (sel == 0) {
    const int m0 = mt * 128;
#pragma unroll
    for (int ii = 0; ii < 4; ++ii)
      Arow[ii] = A + (size_t)(m0 + w * 32 + ii * 8 + lr) * 1024 + scg * 8;
  } else {
    cnt_b = cnt[bI];
    if (r0 >= cnt_b) return;
#pragma unroll
    for (int ii = 0; ii < 4; ++ii) {
      int r = r0 + w * 32 + ii * 8 + lr;
      r = (r < cnt_b) ? r : (cnt_b - 1);
      Arow[ii] = A + (size_t)(bI * 2048 + src[bI * 2048 + r]) * 1024 + scg * 8;
    }
  }
  const unsigned short* Bsrc = W + (size_t)(n0 + w * 32 + lr) * 1024 + scg * 8;

  fx4 acc[4][4] = {};

  for (int kt = 0; kt < 16; ++kt) {
#pragma unroll
    for (int i = 0; i < 4; ++i) {
      async16(Arow[i] + kt * 64, &As[(w * 32 + i * 8) * 64]);
      async16(Bsrc + (size_t)i * 8 * 1024 + kt * 64, &Bs[(w * 32 + i * 8) * 64]);
    }
    __syncthreads();
#pragma unroll
    for (int kk = 0; kk < 2; ++kk) {
      const int kg = kk * 4 + (ln >> 4);
      hfx8 af[4], bfr[4];
#pragma unroll
      for (int mi = 0; mi < 4; ++mi) {
        int row = wr * 64 + mi * 16 + (ln & 15);
        af[mi] = *(const hfx8*)&As[row * 64 + ((kg ^ (row & 7)) * 8)];
      }
#pragma unroll
      for (int ni = 0; ni < 4; ++ni) {
        int row = wc * 64 + ni * 16 + (ln & 15);
        bfr[ni] = *(const hfx8*)&Bs[row * 64 + ((kg ^ (row & 7)) * 8)];
      }
#pragma unroll
      for (int mi = 0; mi < 4; ++mi)
#pragma unroll
        for (int ni = 0; ni < 4; ++ni)
          acc[mi][ni] = __builtin_amdgcn_mfma_f32_16x16x32_f16(af[mi], bfr[ni], acc[mi][ni], 0, 0, 0);
    }
    __syncthreads();
  }
  const int cb = n0 + wc * 64 + (ln & 15);
  const int rloc = wr * 64 + ((ln >> 4) << 2);
  if (sel == 0) {
    const int m0 = mt * 128;
#pragma unroll
    for (int mi = 0; mi < 4; ++mi)
#pragma unroll
      for (int ni = 0; ni < 4; ++ni)
#pragma unroll
        for (int j = 0; j < 4; ++j)
          Qf[(size_t)(m0 + rloc + mi * 16 + j) * 1024 + cb + ni * 16] = f2h(acc[mi][ni][j]);
  } else if (sel == 1) {
    // K dense into compacted rows
#pragma unroll
    for (int mi = 0; mi < 4; ++mi)
#pragma unroll
      for (int ni = 0; ni < 4; ++ni)
#pragma unroll
        for (int j = 0; j < 4; ++j)
          Kf[(size_t)(bI * 2048 + r0 + rloc + mi * 16 + j) * 1024 + cb + ni * 16] = f2h(acc[mi][ni][j]);
  } else {
    // V^T compacted: Vt[((bI*16+h2)*64+d2)][r0 + rloc + mi*16 .. +3] (usx4)
#pragma unroll
    for (int mi = 0; mi < 4; ++mi)
#pragma unroll
      for (int ni = 0; ni < 4; ++ni) {
        int c = cb + ni * 16;
        int h2 = (c >> 6) & 15, d2 = c & 63;
        usx4 pk;
#pragma unroll
        for (int j = 0; j < 4; ++j) pk[j] = f2h(acc[mi][ni][j]);
        *(usx4*)&Vt[((size_t)(bI * 16 + h2) * 64 + d2) * 2048 + r0 + rloc + mi * 16] = pk;
      }
  }
}

// O-projection fp16: C = A[4096][1024] * W^T, f32 out.
// Grid 256 = 1 block/CU -> DOUBLE-buffered prefetch (single-buffer at 1
// block/CU is the R17 regression mode: nothing hides the stage drain).
__global__ __launch_bounds__(256, 2)
void gemm_o(const unsigned short* __restrict__ A,
            const unsigned short* __restrict__ W,
            float* __restrict__ O) {
  __shared__ unsigned short As[2][128 * 64];
  __shared__ unsigned short Bs[2][128 * 64];
  const int tid = threadIdx.x;
  const int w = tid >> 6, ln = tid & 63;
  const int mt = blockIdx.x, nt = blockIdx.y;
  const int m0 = mt * 128, n0 = nt * 128;
  const int wr = w >> 1, wc = w & 1;
  fx4 acc[4][4] = {};
  const int lr = ln >> 3;
  const int scg = (ln & 7) ^ lr;
  const unsigned short* Asrc = A + (size_t)(m0 + w * 32 + lr) * 1024 + scg * 8;
  const unsigned short* Bsrc = W + (size_t)(n0 + w * 32 + lr) * 1024 + scg * 8;

#define G_STAGE(KT, BI)                                                        \
  {                                                                            \
    _Pragma("unroll") for (int i = 0; i < 4; ++i) {                            \
      async16(Asrc + (size_t)i * 8 * 1024 + (KT) * 64, &As[BI][(w * 32 + i * 8) * 64]); \
      async16(Bsrc + (size_t)i * 8 * 1024 + (KT) * 64, &Bs[BI][(w * 32 + i * 8) * 64]); \
    }                                                                          \
  }

  G_STAGE(0, 0);
  for (int kt = 0; kt < 16; ++kt) {
    const int cur = kt & 1;
    __syncthreads();
    if (kt < 15) G_STAGE(kt + 1, cur ^ 1);
#pragma unroll
    for (int kk = 0; kk < 2; ++kk) {
      const int kg = kk * 4 + (ln >> 4);
      hfx8 af[4], bfr[4];
#pragma unroll
      for (int mi = 0; mi < 4; ++mi) {
        int row = wr * 64 + mi * 16 + (ln & 15);
        af[mi] = *(const hfx8*)&As[cur][row * 64 + ((kg ^ (row & 7)) * 8)];
      }
#pragma unroll
      for (int ni = 0; ni < 4; ++ni) {
        int row = wc * 64 + ni * 16 + (ln & 15);
        bfr[ni] = *(const hfx8*)&Bs[cur][row * 64 + ((kg ^ (row & 7)) * 8)];
      }
#pragma unroll
      for (int mi = 0; mi < 4; ++mi)
#pragma unroll
        for (int ni = 0; ni < 4; ++ni)
          acc[mi][ni] = __builtin_amdgcn_mfma_f32_16x16x32_f16(af[mi], bfr[ni], acc[mi][ni], 0, 0, 0);
    }
  }
#undef G_STAGE
  const int cb = n0 + wc * 64 + (ln & 15);
  const int rb = m0 + wr * 64 + ((ln >> 4) << 2);
#pragma unroll
  for (int mi = 0; mi < 4; ++mi)
#pragma unroll
    for (int ni = 0; ni < 4; ++ni)
#pragma unroll
      for (int j = 0; j < 4; ++j)
        O[(size_t)(rb + mi * 16 + j) * 1024 + cb + ni * 16] = acc[mi][ni][j];
}

// Flash attention fp16 on 32x32x16 MFMA over COMPACTED keys.
// Grid 512 (2 blocks/CU), DOUBLE-buffered K/V, 4 waves (R16/R18-proven optimum).
// Cross-half exchange via __builtin_amdgcn_permlane32_swap (VALU pipe).
__global__ __launch_bounds__(256, 2)
void attn_fwd(const unsigned short* __restrict__ Qf,
              const unsigned short* __restrict__ Kf,
              const unsigned short* __restrict__ Vt,
              const int* __restrict__ cnt,
              unsigned short* __restrict__ Ov) {
  __shared__ __align__(16) unsigned short smem[32768];  // 64KB
  unsigned short (*Ks)[8192] = (unsigned short (*)[8192])(smem);          // 2 x 16KB
  unsigned short (*Vs)[8192] = (unsigned short (*)[8192])(smem + 16384);  // 2 x 16KB
  unsigned short* eb = smem;                                              // epilogue reuse

  const int tid = threadIdx.x;
  const int w = tid >> 6, ln = tid & 63;
  const int bid = blockIdx.x;
  const int wg = (bid & 7) * 64 + (bid >> 3);  // XCD-chunk swizzle (bijective)
  const int qt = wg & 15, h = (wg >> 4) & 15, b = wg >> 8;
  const int l31 = ln & 31, h5 = ln >> 5;
  const int q = qt * 128 + w * 32 + l31;

  const int cnt_b = cnt[b];
  const int ntile = (cnt_b + 127) >> 7;

  // Q as B-fragments: lane holds Q[q][d = dc*16 + h5*8 + 0..7]
  hfx8 qb[4];
  {
    const unsigned short* qp = Qf + (size_t)(b * 2048 + q) * 1024 + h * 64 + h5 * 8;
    qb[0] = *(const hfx8*)(qp);
    qb[1] = *(const hfx8*)(qp + 16);
    qb[2] = *(const hfx8*)(qp + 32);
    qb[3] = *(const hfx8*)(qp + 48);
  }

  fx16 o0 = {}, o1 = {};
  float mrow = -INFINITY, lrow = 0.f;
  const fp16x2 one2 = { (__fp16)1.0f, (__fp16)1.0f };

  // Staging (4 waves): K: wave stages 32 rows (4 chunks of 8 rows x 64d);
  //                    V: wave stages 16 rows (4 chunks of 4 rows x 128s).
  // Swizzle keys: K row&7 = ln>>3 ; V row&7 = (ii*4 + (ln>>4)) & 7.
#define A_STAGE(KT, BI)                                                          \
  {                                                                              \
    _Pragma("unroll") for (int ii = 0; ii < 4; ++ii) {                           \
      int krow = w * 32 + ii * 8 + (ln >> 3);                                    \
      async16(Kf + ((size_t)(b * 2048 + (KT) * 128 + krow)) * 1024 + h * 64 +    \
                  (((ln & 7) ^ (ln >> 3)) * 8),                                  \
              &Ks[BI][(w * 4 + ii) * 512]);                                      \
      int vswz = (ii * 4 + (ln >> 4)) & 7;                                       \
      int vrow = w * 16 + ii * 4 + (ln >> 4);                                    \
      async16(Vt + ((size_t)((b * 16 + h) * 64 + vrow)) * 2048 + (KT) * 128 +    \
                  (((ln & 15) ^ vswz) * 8),                                      \
              &Vs[BI][(w * 4 + ii) * 512]);                                      \
    }                                                                            \
  }

  A_STAGE(0, 0);
  for (int kt = 0; kt < ntile; ++kt) {
    const int cur = kt & 1;
    __syncthreads();
    if (kt + 1 < ntile) A_STAGE(kt + 1, cur ^ 1);
    const bool lastt = (kt == ntile - 1);

    // QK: s[kb] C[key = kb*32 + crow(reg,h5)][q = l31]; C-init 0, or tail-mask on last tile
    fx16 sArr[4];
#pragma unroll
    for (int kb = 0; kb < 4; ++kb) {
      fx16 z = {};
      if (lastt) {
#pragma unroll
        for (int r = 0; r < 16; ++r) {
          int crow = (r & 3) + 8 * (r >> 2) + 4 * h5;
          int key = kt * 128 + kb * 32 + crow;
          z[r] = (key < cnt_b) ? 0.0f : -1e30f;
        }
      }
#pragma unroll
      for (int dc = 0; dc < 4; ++dc) {
        int row = kb * 32 + l31;
        int slot = (dc * 2 + h5) ^ (l31 & 7);
        hfx8 a = *(const hfx8*)&Ks[cur][row * 64 + slot * 8];
        z = __builtin_amdgcn_mfma_f32_32x32x16_f16(a, qb[dc], z, 0, 0, 0);
      }
      sArr[kb] = z;
    }

    // online softmax (per-q state lane-local; partner = lane^32 via permlane swap).
    float tm = -INFINITY;
#pragma unroll
    for (int kb = 0; kb < 4; ++kb)
#pragma unroll
      for (int j = 0; j < 8; ++j)
        tm = fmaxf(fmaxf(sArr[kb][2 * j], sArr[kb][2 * j + 1]), tm);
    {
      auto t = __builtin_amdgcn_permlane32_swap(__float_as_uint(tm), __float_as_uint(tm), false, false);
      tm = fmaxf(__uint_as_float(t[0]), __uint_as_float(t[1]));
    }
    if (!__all(tm <= mrow + 8.0f)) {
      float mn = fmaxf(mrow, tm);
      float fac = exp2f((mrow - mn) * LOG2E);
      mrow = mn;
      lrow *= fac;
#pragma unroll
      for (int r = 0; r < 16; ++r) { o0[r] *= fac; o1[r] *= fac; }
    }
    const float nm2 = -mrow * LOG2E;
    float psum = 0.f;
    unsigned int pk[4][8];
#pragma unroll
    for (int kb = 0; kb < 4; ++kb) {
#pragma unroll
      for (int j = 0; j < 8; ++j) {
        float pa = exp2f(fmaf(sArr[kb][2 * j], LOG2E, nm2));
        float pb = exp2f(fmaf(sArr[kb][2 * j + 1], LOG2E, nm2));
        union { fp16x2 h; unsigned int u; } rr;
        rr.h = __builtin_amdgcn_cvt_pkrtz(pa, pb);
        pk[kb][j] = rr.u;
        psum = __builtin_amdgcn_fdot2(rr.h, one2, psum, false);
      }
    }
    {
      auto t = __builtin_amdgcn_permlane32_swap(__float_as_uint(psum), __float_as_uint(psum), false, false);
      psum = __uint_as_float(t[0]) + __uint_as_float(t[1]);
    }
    lrow += psum;

    // PV: O^T[d][q] += V^T x P^T. B-frag via permlane32_swap.
#pragma unroll
    for (int kc = 0; kc < 8; ++kc) {
      const int kbq = kc >> 1;
      const int jb = (kc & 1) * 4;
      auto r0 = __builtin_amdgcn_permlane32_swap(pk[kbq][jb], pk[kbq][jb + 2], false, false);
      auto r1 = __builtin_amdgcn_permlane32_swap(pk[kbq][jb + 1], pk[kbq][jb + 3], false, false);
      union { unsigned int u[4]; hfx8 v; } B_;
      B_.u[0] = (unsigned int)r0[0];
      B_.u[1] = (unsigned int)r1[0];
      B_.u[2] = (unsigned int)r0[1];
      B_.u[3] = (unsigned int)r1[1];
      int slot = (kc * 2 + h5) ^ (l31 & 7);
      hfx8 va0 = *(const hfx8*)&Vs[cur][(l31) * 128 + slot * 8];
      o0 = __builtin_amdgcn_mfma_f32_32x32x16_f16(va0, B_.v, o0, 0, 0, 0);
      hfx8 va1 = *(const hfx8*)&Vs[cur][(32 + l31) * 128 + slot * 8];
      o1 = __builtin_amdgcn_mfma_f32_32x32x16_f16(va1, B_.v, o1, 0, 0, 0);
    }
  }
#undef A_STAGE

  // epilogue: divide, transpose via LDS (rows padded to 88 u16 = 176B, 16B-aligned),
  // coalesced store to Av[q][h*64+d]
  __syncthreads();  // all waves done reading K/V LDS before overwrite
  float inv = 1.0f / lrow;
  const int ql = w * 32 + l31;
#pragma unroll
  for (int db = 0; db < 2; ++db) {
#pragma unroll
    for (int r4 = 0; r4 < 4; ++r4) {
      float v0 = (db ? o1[4 * r4] : o0[4 * r4]) * inv;
      float v1 = (db ? o1[4 * r4 + 1] : o0[4 * r4 + 1]) * inv;
      float v2 = (db ? o1[4 * r4 + 2] : o0[4 * r4 + 2]) * inv;
      float v3 = (db ? o1[4 * r4 + 3] : o0[4 * r4 + 3]) * inv;
      union { fp16x2 h; unsigned int u; } pa_, pb_;
      pa_.h = __builtin_amdgcn_cvt_pkrtz(v0, v1);
      pb_.h = __builtin_amdgcn_cvt_pkrtz(v2, v3);
      ux2 tw; tw[0] = pa_.u; tw[1] = pb_.u;
      int d_base = db * 32 + 8 * r4 + 4 * h5;
      *(ux2*)&eb[ql * 88 + d_base] = tw;
    }
  }
  __syncthreads();
#pragma unroll
  for (int pass = 0; pass < 4; ++pass) {
    int idx = pass * 256 + tid;
    int qq = idx >> 3, slot = idx & 7;
    usx8 vv = *(const usx8*)&eb[qq * 88 + slot * 8];
    *(usx8*)&Ov[(size_t)(b * 2048 + qt * 128 + qq) * 1024 + h * 64 + slot * 8] = vv;
  }
}

// out = LayerNorm(h + attn_out) * g + b ; one block per row
__global__ __launch_bounds__(256)
void lnk(const float* __restrict__ h, const float* __restrict__ ao,
         const float* __restrict__ g, const float* __restrict__ bb,
         float* __restrict__ out) {
  const int row = blockIdx.x;
  const int tid = threadIdx.x;
  const size_t base = (size_t)row * 1024 + tid * 4;
  fx4 x = *(const fx4*)(h + base);
  fx4 a = *(const fx4*)(ao + base);
  x = x + a;
  float s = x[0] + x[1] + x[2] + x[3];
  float q = x[0] * x[0] + x[1] * x[1] + x[2] * x[2] + x[3] * x[3];
#pragma unroll
  for (int mm = 1; mm < 64; mm <<= 1) {
    s += __shfl_xor(s, mm);
    q += __shfl_xor(q, mm);
  }
  __shared__ float rs[4], rq[4];
  if ((tid & 63) == 0) { rs[tid >> 6] = s; rq[tid >> 6] = q; }
  __syncthreads();
  s = rs[0] + rs[1] + rs[2] + rs[3];
  q = rq[0] + rq[1] + rq[2] + rq[3];
  float mu = s * (1.0f / 1024.0f);
  float var = q * (1.0f / 1024.0f) - mu * mu;
  float rstd = rsqrtf(var + 1e-5f);
  fx4 gg = *(const fx4*)(g + tid * 4);
  fx4 bv = *(const fx4*)(bb + tid * 4);
  fx4 ov;
#pragma unroll
  for (int k = 0; k < 4; ++k) ov[k] = (x[k] - mu) * rstd * gg[k] + bv[k];
  *(fx4*)(out + base) = ov;
}

extern "C" void kernel_launch(void* const* d_in, const int* in_sizes, int n_in,
                              void* d_out, int out_size, void* d_ws, size_t ws_size,
                              hipStream_t stream) {
  const float* h = (const float*)d_in[0];
  const int* msk = (const int*)d_in[1];
  const float* qw = (const float*)d_in[2];
  const float* kw = (const float*)d_in[3];
  const float* vw = (const float*)d_in[4];
  const float* ow = (const float*)d_in[5];
  const float* lng = (const float*)d_in[6];
  const float* lnb = (const float*)d_in[7];
  float* out = (float*)d_out;
  char* ws = (char*)d_ws;

  const size_t MB = 1u << 20;
  unsigned short* h16 = (unsigned short*)(ws + 0 * MB);   // 8 MB
  unsigned short* w16q = (unsigned short*)(ws + 8 * MB);  // 2 MB
  unsigned short* w16k = (unsigned short*)(ws + 10 * MB); // 2 MB
  unsigned short* w16v = (unsigned short*)(ws + 12 * MB); // 2 MB
  unsigned short* w16o = (unsigned short*)(ws + 14 * MB); // 2 MB
  unsigned short* Qf  = (unsigned short*)(ws + 16 * MB);  // 8 MB
  unsigned short* Kf  = (unsigned short*)(ws + 24 * MB);  // 8 MB
  unsigned short* Vtb = (unsigned short*)(ws + 32 * MB);  // 8 MB
  unsigned short* Av  = (unsigned short*)(ws + 40 * MB);  // 8 MB
  float* Ao = (float*)(ws + 48 * MB);                     // 16 MB
  // src/cnt live in the Ao region (read by gemm_qkv/attn, both before gemm_o)
  int* srcIdx = (int*)(ws + 48 * MB);                     // 16 KB
  int* cnt    = (int*)(ws + 48 * MB + 16384);             // 8 B

  prep<<<dim3(8194), 256, 0, stream>>>(h, qw, kw, vw, ow, msk,
                                       h16, w16q, w16k, w16v, w16o, srcIdx, cnt);
  gemm_qkv<<<dim3(768), 256, 0, stream>>>(h16, w16q, w16k, w16v, srcIdx, cnt, Qf, Kf, Vtb);
  attn_fwd<<<dim3(512), 256, 0, stream>>>(Qf, Kf, Vtb, cnt, Av);
  gemm_o<<<dim3(32, 8), 256, 0, stream>>>(Av, w16o, Ao);
  lnk<<<dim3(4096), 256, 0, stream>>>(h, Ao, lng, lnb, out);
}